// Round 6
// baseline (269.484 us; speedup 1.0000x reference)
//
#include <hip/hip_runtime.h>
#include <stdint.h>

#define NL      8192
#define NH      32768
#define FDIM    128
#define KSEL    32
#define QPW     2                 // queries per wave
#define NWAVES  2
#define BLOCK   (NWAVES * 64)     // 128
#define QPB     (NWAVES * QPW)    // 4 queries per block
#define BUFCAP  256
#define NGROUP  (NL / 64)         // 128 groups of 64 sorted points
#define NCELL   4096              // 16^3 Morton cells
#define TSCAN   4                 // nearest groups scanned for tau
#define MAXPASS 6

__device__ __forceinline__ int imin(int a, int b) { return a < b ? a : b; }
__device__ __forceinline__ int imax(int a, int b) { return a > b ? a : b; }

// ---- ballot rank-select: smallest nonneg int key t with count(keys<=t)>=rank.
__device__ __forceinline__ int rank_select2(int k0, int k1, int rank) {
    unsigned lo = 0u, hi = 0x7F800000u;
    while (lo < hi) {
        const int mid = (int)((lo + hi) >> 1);
        const int cnt = (int)__popcll(__ballot(k0 <= mid))
                      + (int)__popcll(__ballot(k1 <= mid));
        if (cnt >= rank) hi = (unsigned)mid; else lo = (unsigned)mid + 1u;
    }
    return (int)lo;
}
__device__ __forceinline__ int rank_select4(const int* k, int rank) {
    unsigned lo = 0u, hi = 0x7F800000u;
    while (lo < hi) {
        const int mid = (int)((lo + hi) >> 1);
        int cnt = 0;
#pragma unroll
        for (int r = 0; r < 4; ++r)
            cnt += (int)__popcll(__ballot(k[r] <= mid));
        if (cnt >= rank) hi = (unsigned)mid; else lo = (unsigned)mid + 1u;
    }
    return (int)lo;
}

// ---- Morton cell id: 16^3 grid over [-4,4], cell size 0.5 ----
__device__ __forceinline__ uint32_t spread3(uint32_t x) {
    x &= 0xFu;
    x = (x | (x << 16)) & 0x030000FFu;
    x = (x | (x << 8))  & 0x0300F00Fu;
    x = (x | (x << 4))  & 0x030C30C3u;
    x = (x | (x << 2))  & 0x09249249u;
    return x;
}
__device__ __forceinline__ int cell_of(float px, float py, float pz) {
    int ix = (int)floorf((px + 4.0f) * 2.0f);
    int iy = (int)floorf((py + 4.0f) * 2.0f);
    int iz = (int)floorf((pz + 4.0f) * 2.0f);
    ix = imin(imax(ix, 0), 15); iy = imin(imax(iy, 0), 15); iz = imin(imax(iz, 0), 15);
    return (int)(spread3((uint32_t)ix) | (spread3((uint32_t)iy) << 1) | (spread3((uint32_t)iz) << 2));
}

// ======= P1: LDS histogram + scan -> global cursor (1 block, 1024 thr) =======
__global__ __launch_bounds__(1024)
void k_hist_scan(const float* __restrict__ pos_l, int* __restrict__ cursor) {
    __shared__ int hist[NCELL];     // 16 KB
    __shared__ int wpart[16];
    const int tid = threadIdx.x, lane = tid & 63, wv = tid >> 6;
    for (int i = tid; i < NCELL; i += 1024) hist[i] = 0;
    __syncthreads();
#pragma unroll
    for (int r = 0; r < 8; ++r) {
        const int i = r * 1024 + tid;
        const int c = cell_of(pos_l[i * 3 + 0], pos_l[i * 3 + 1], pos_l[i * 3 + 2]);
        atomicAdd(&hist[c], 1);
    }
    __syncthreads();
    int loc[4]; int ts = 0;
#pragma unroll
    for (int i = 0; i < 4; ++i) { loc[i] = ts; ts += hist[tid * 4 + i]; }
    int incl = ts;
#pragma unroll
    for (int d = 1; d < 64; d <<= 1) {
        const int t = __shfl_up(incl, d);
        if (lane >= d) incl += t;
    }
    if (lane == 63) wpart[wv] = incl;
    __syncthreads();
    int base = 0;
    for (int j = 0; j < wv; ++j) base += wpart[j];
    const int texcl = base + incl - ts;
#pragma unroll
    for (int i = 0; i < 4; ++i) cursor[tid * 4 + i] = texcl + loc[i];
}

// ======= P2: scatter into cell-sorted order (32 blocks x 256) =======
__global__ __launch_bounds__(256)
void k_scatter(const float* __restrict__ pos_l, int* __restrict__ cursor,
               float4* __restrict__ sorted, int* __restrict__ oidx) {
    const int i = blockIdx.x * 256 + threadIdx.x;
    const float px = pos_l[i * 3 + 0];
    const float py = pos_l[i * 3 + 1];
    const float pz = pos_l[i * 3 + 2];
    const int c = cell_of(px, py, pz);
    const int pos = atomicAdd(&cursor[c], 1);
    sorted[pos] = make_float4(px, py, pz, fmaf(px, px, fmaf(py, py, pz * pz)));
    oidx[pos] = i;
}

// ======= P3: per-group AABBs (2 blocks x 1024; wave handles 4 groups) =======
__global__ __launch_bounds__(1024)
void k_boxes(const float4* __restrict__ sorted,
             float4* __restrict__ box_c, float4* __restrict__ box_e) {
    const int lane = threadIdx.x & 63;
    const int wv   = threadIdx.x >> 6;
#pragma unroll
    for (int r = 0; r < 4; ++r) {
        const int g = (blockIdx.x * 16 + wv) * 4 + r;
        const float4 p = sorted[g * 64 + lane];
        float mnx = p.x, mxx = p.x, mny = p.y, mxy = p.y, mnz = p.z, mxz = p.z;
#pragma unroll
        for (int j = 32; j >= 1; j >>= 1) {
            mnx = fminf(mnx, __shfl_xor(mnx, j)); mxx = fmaxf(mxx, __shfl_xor(mxx, j));
            mny = fminf(mny, __shfl_xor(mny, j)); mxy = fmaxf(mxy, __shfl_xor(mxy, j));
            mnz = fminf(mnz, __shfl_xor(mnz, j)); mxz = fmaxf(mxz, __shfl_xor(mxz, j));
        }
        if (lane == 0) {
            box_c[g] = make_float4((mnx + mxx) * 0.5f, (mny + mxy) * 0.5f, (mnz + mxz) * 0.5f, 0.0f);
            box_e[g] = make_float4((mxx - mnx) * 0.5f + 1e-4f, (mxy - mny) * 0.5f + 1e-4f,
                                   (mxz - mnz) * 0.5f + 1e-4f, 0.0f);
        }
    }
}

// =================== Main kernel ===================
__global__ __launch_bounds__(BLOCK)
void knn_interp_kernel(const float* __restrict__ x,
                       const float* __restrict__ pos_h,
                       const float4* __restrict__ sorted,
                       const float4* __restrict__ box_c,
                       const float4* __restrict__ box_e,
                       const int* __restrict__ oidx,
                       float* __restrict__ out)
{
    __shared__ uint16_t s_idx[QPB][BUFCAP];                // 2 KB
    __shared__ float    s_w[QPB][KSEL];                    // 512 B
    __shared__ int      s_wi[QPB][KSEL];                   // 512 B
    __shared__ unsigned long long s_surv[QPB][2];          // 64 B
    __shared__ float4   s_qp[QPB];                         // qx,qy,qz,h2
    __shared__ float    s_tau[QPB];                        // tau in D-space

    const int tid   = threadIdx.x;
    const int lane  = tid & 63;
    const int wid   = tid >> 6;
    const int qbase = blockIdx.x * QPB + wid * QPW;
    const unsigned long long mlt = (1ull << lane) - 1ull;  // bits strictly below lane

    // lane owns box `lane` (A) and `lane+64` (B)
    const float4 cAc = box_c[lane];
    const float4 cBc = box_c[lane + 64];
    const float4 cAe = box_e[lane];
    const float4 cBe = box_e[lane + 64];

    // ---- Phase 1: per query tau (4 nearest boxes -> 256-pt scan ->
    //      bitonic-64 32nd-smallest) + box-survival masks ----
#pragma unroll 1
    for (int q = 0; q < QPW; ++q) {
        const int QQ = wid * QPW + q;
        const int gq = qbase + q;
        const float ax = pos_h[gq * 3 + 0];
        const float ay = pos_h[gq * 3 + 1];
        const float az = pos_h[gq * 3 + 2];
        const float h2 = fmaf(ax, ax, fmaf(ay, ay, az * az));
        s_qp[QQ] = make_float4(ax, ay, az, h2);

        // box distance^2 (lower bound on any point's d2 in the box)
        float dx = fmaxf(fabsf(ax - cAc.x) - cAe.x, 0.0f);
        float dy = fmaxf(fabsf(ay - cAc.y) - cAe.y, 0.0f);
        float dz = fmaxf(fabsf(az - cAc.z) - cAe.z, 0.0f);
        const float dA = fmaf(dx, dx, fmaf(dy, dy, dz * dz));
        dx = fmaxf(fabsf(ax - cBc.x) - cBe.x, 0.0f);
        dy = fmaxf(fabsf(ay - cBc.y) - cBe.y, 0.0f);
        dz = fmaxf(fabsf(az - cBc.z) - cBe.z, 0.0f);
        const float dB = fmaf(dx, dx, fmaf(dy, dy, dz * dz));

        // 4 nearest groups by box distance (ids unique -> keys distinct)
        const int kA = (int)((__float_as_uint(dA) & 0xFFFFFF00u) | (uint32_t)lane);
        const int kB = (int)((__float_as_uint(dB) & 0xFFFFFF00u) | (uint32_t)(lane + 64));
        const int t4 = rank_select2(kA, kB, TSCAN);
        unsigned long long gm0 = __ballot(kA <= t4);
        unsigned long long gm1 = __ballot(kB <= t4);

        // scan 256 points; per-lane min of D = |p|^2 - 2 q.p
        float dmin = INFINITY;
#pragma unroll 1
        for (int t = 0; t < TSCAN; ++t) {
            int g;
            if (gm0) { g = __builtin_ctzll(gm0); gm0 &= gm0 - 1ull; }
            else     { g = 64 + __builtin_ctzll(gm1); gm1 &= gm1 - 1ull; }
            const float4 p = sorted[(g << 6) + lane];
            const float s = fmaf(ax, p.x, fmaf(ay, p.y, az * p.z));
            dmin = fminf(dmin, fmaf(-2.0f, s, p.w));
        }
        // bitonic-64 ascending (R2-verified); 32 lanes witness 32 distinct
        // points <= element31 => tau >= true 32nd d2
        float v = dmin;
#pragma unroll
        for (int k = 2; k <= 64; k <<= 1) {
#pragma unroll
            for (int j = k >> 1; j >= 1; j >>= 1) {
                const float o     = __shfl_xor(v, j);
                const bool  up    = ((lane & k) == 0);
                const bool  lower = ((lane & j) == 0);
                v = (lower == up) ? fminf(v, o) : fmaxf(v, o);
            }
        }
        const float tauD = __shfl(v, 31) + 1e-4f;       // D-space + margin
        s_tau[QQ] = tauD;
        const float tau_d2 = fmaxf(tauD + h2, 0.0f) + 1e-3f;  // d2-space, padded
        s_surv[QQ][0] = __ballot(dA <= tau_d2);
        s_surv[QQ][1] = __ballot(dB <= tau_d2);
    }

    // ---- Phase 2: per query: prefetched collect (w/ overflow tightening) ->
    //      exact fp64 re-rank (bitonic-128) -> gather + weighted average ----
#pragma unroll 1
    for (int q = 0; q < QPW; ++q) {
        const int QQ = wid * QPW + q;
        const int gq = qbase + q;
        const float4 qp = s_qp[QQ];
        const float ax = qp.x, ay = qp.y, az = qp.z, h2 = qp.w;
        float tau = s_tau[QQ];
        int M = 0;

#pragma unroll 1
        for (int pass = 0; pass < MAXPASS; ++pass) {
            M = 0;
            unsigned long long m0 = s_surv[QQ][0];
            unsigned long long m1 = s_surv[QQ][1];
            int g_cur = -1;
            if (m0)      { g_cur = __builtin_ctzll(m0); m0 &= m0 - 1ull; }
            else if (m1) { g_cur = 64 + __builtin_ctzll(m1); m1 &= m1 - 1ull; }
            float4 pc = make_float4(0, 0, 0, 0);
            if (g_cur >= 0) pc = sorted[(g_cur << 6) + lane];
#pragma unroll 1
            while (g_cur >= 0) {
                int g_nxt = -1;     // prefetch next group before the ballot
                if (m0)      { g_nxt = __builtin_ctzll(m0); m0 &= m0 - 1ull; }
                else if (m1) { g_nxt = 64 + __builtin_ctzll(m1); m1 &= m1 - 1ull; }
                float4 pn = pc;
                if (g_nxt >= 0) pn = sorted[(g_nxt << 6) + lane];

                const float s = fmaf(ax, pc.x, fmaf(ay, pc.y, az * pc.z));
                const float D = fmaf(-2.0f, s, pc.w);
                const bool hit = (D <= tau);
                const unsigned long long b = __ballot(hit);
                if (b) {
                    const int o = M + (int)__popcll(b & mlt);
                    if (hit && o < BUFCAP) s_idx[QQ][o] = (uint16_t)((g_cur << 6) + lane);
                    M += (int)__popcll(b);
                }
                g_cur = g_nxt; pc = pn;
            }
            if (M <= BUFCAP) break;
            // overflow: tighten tau to exact 32nd-smallest d2 of the 256
            // buffered (order stat of a subset => still >= global 32nd).
            int kk[4];
#pragma unroll
            for (int r = 0; r < 4; ++r) {
                const int idx = (int)s_idx[QQ][64 * r + lane];
                const float4 c = sorted[idx];
                const float s = fmaf(ax, c.x, fmaf(ay, c.y, az * c.z));
                const float d2 = fmaxf(fmaf(-2.0f, s, c.w) + h2, 0.0f);
                kk[r] = __float_as_int(d2);
            }
            const int tk = rank_select4(kk, KSEL);
            tau = __int_as_float(tk) + 1e-4f - h2;   // back to D-space + margin
        }
        if (M > BUFCAP) M = BUFCAP;

        // -------- exact fp64 re-rank + top-32 selection --------
        const double axd = (double)ax, ayd = (double)ay, azd = (double)az;
        if (M <= 128) {
            // R2-verified bitonic-128, 2 elems/lane
            const int i0 = (2 * lane     < M) ? (int)s_idx[QQ][2 * lane]     : -1;
            const int i1 = (2 * lane + 1 < M) ? (int)s_idx[QQ][2 * lane + 1] : -1;
            float f0 = INFINITY, f1 = INFINITY;
            if (i0 >= 0) {
                const float4 c = sorted[i0];
                const double dxd = (double)c.x - axd, dyd = (double)c.y - ayd, dzd = (double)c.z - azd;
                f0 = (float)(dxd * dxd + dyd * dyd + dzd * dzd);
            }
            if (i1 >= 0) {
                const float4 c = sorted[i1];
                const double dxd = (double)c.x - axd, dyd = (double)c.y - ayd, dzd = (double)c.z - azd;
                f1 = (float)(dxd * dxd + dyd * dyd + dzd * dzd);
            }
            int v0 = __float_as_int(f0);
            int v1 = __float_as_int(f1);
#pragma unroll
            for (int k = 2; k <= 128; k <<= 1) {
                const bool up = ((lane & (k >> 1)) == 0);
#pragma unroll
                for (int j = k >> 1; j >= 2; j >>= 1) {
                    const int  xo    = j >> 1;
                    const bool lower = ((lane & xo) == 0);
                    const int o0 = __shfl_xor(v0, xo);
                    const int o1 = __shfl_xor(v1, xo);
                    v0 = (lower == up) ? imin(v0, o0) : imax(v0, o0);
                    v1 = (lower == up) ? imin(v1, o1) : imax(v1, o1);
                }
                const int mn = imin(v0, v1), mx = imax(v0, v1);  // j == 1
                v0 = up ? mn : mx;
                v1 = up ? mx : mn;
            }
            const int tau32 = __shfl(v1, 15);   // element 31 = 32nd smallest
            const bool a0 = (i0 >= 0) && (__float_as_int(f0) <= tau32);
            const bool a1 = (i1 >= 0) && (__float_as_int(f1) <= tau32);
            const unsigned long long b0 = __ballot(a0);
            const unsigned long long b1 = __ballot(a1);
            const int base = (int)__popcll(b0 & mlt) + (int)__popcll(b1 & mlt);
            const int p0 = base;
            const int p1 = base + (a0 ? 1 : 0);
            if (a0 && p0 < KSEL) { s_w[QQ][p0] = 1.0f / fmaxf(f0, 1e-16f); s_wi[QQ][p0] = oidx[i0]; }
            if (a1 && p1 < KSEL) { s_w[QQ][p1] = 1.0f / fmaxf(f1, 1e-16f); s_wi[QQ][p1] = oidx[i1]; }
        } else {
            // rare path (128 < M <= 256): ballot rank-select, 4 elems/lane
            int ii[4]; float ff[4]; int kk_[4];
#pragma unroll
            for (int r = 0; r < 4; ++r) {
                const int e = 4 * lane + r;
                ii[r] = (e < M) ? (int)s_idx[QQ][e] : -1;
                ff[r] = INFINITY;
                if (ii[r] >= 0) {
                    const float4 c = sorted[ii[r]];
                    const double dxd = (double)c.x - axd, dyd = (double)c.y - ayd, dzd = (double)c.z - azd;
                    ff[r] = (float)(dxd * dxd + dyd * dyd + dzd * dzd);
                }
                kk_[r] = __float_as_int(ff[r]);
            }
            const int tau32 = rank_select4(kk_, KSEL);
            bool a[4]; unsigned long long b[4];
#pragma unroll
            for (int r = 0; r < 4; ++r) {
                a[r] = (ii[r] >= 0) && (kk_[r] <= tau32);
                b[r] = __ballot(a[r]);
            }
            int base = 0;
#pragma unroll
            for (int r = 0; r < 4; ++r) base += (int)__popcll(b[r] & mlt);
            int pref = 0;
#pragma unroll
            for (int r = 0; r < 4; ++r) {
                const int p = base + pref;
                if (a[r] && p < KSEL) { s_w[QQ][p] = 1.0f / fmaxf(ff[r], 1e-16f); s_wi[QQ][p] = oidx[ii[r]]; }
                pref += (a[r] ? 1 : 0);
            }
        }

        // -------- gather + inverse-d2 weighted average --------
        float acc0 = 0.0f, acc1 = 0.0f, wsum = 0.0f;
#pragma unroll 8
        for (int t = 0; t < KSEL; ++t) {
            const float w   = s_w[QQ][t];
            const int   idx = s_wi[QQ][t];
            const float* row = x + (size_t)idx * FDIM;
            acc0 = fmaf(w, row[lane], acc0);
            acc1 = fmaf(w, row[lane + 64], acc1);
            wsum += w;
        }
        const float invw = 1.0f / wsum;
        out[(size_t)gq * FDIM + lane]      = acc0 * invw;
        out[(size_t)gq * FDIM + 64 + lane] = acc1 * invw;
    }
}

extern "C" void kernel_launch(void* const* d_in, const int* in_sizes, int n_in,
                              void* d_out, int out_size, void* d_ws, size_t ws_size,
                              hipStream_t stream) {
    const float* x     = (const float*)d_in[0];
    const float* pos_l = (const float*)d_in[1];
    const float* pos_h = (const float*)d_in[2];
    float* out = (float*)d_out;

    char* ws = (char*)d_ws;
    float4* sorted = (float4*)(ws + 0);         // 128 KB
    int*    oidx   = (int*)(ws + 131072);       // 32 KB
    float4* box_c  = (float4*)(ws + 163840);    // 2 KB
    float4* box_e  = (float4*)(ws + 165888);    // 2 KB
    int*    cursor = (int*)(ws + 167936);       // 16 KB

    hipLaunchKernelGGL(k_hist_scan, dim3(1), dim3(1024), 0, stream, pos_l, cursor);
    hipLaunchKernelGGL(k_scatter, dim3(NL / 256), dim3(256), 0, stream, pos_l, cursor, sorted, oidx);
    hipLaunchKernelGGL(k_boxes, dim3(2), dim3(1024), 0, stream, sorted, box_c, box_e);
    hipLaunchKernelGGL(knn_interp_kernel, dim3(NH / QPB), dim3(BLOCK), 0, stream,
                       x, pos_h, sorted, box_c, box_e, oidx, out);
}